// Round 5
// baseline (464.610 us; speedup 1.0000x reference)
//
#include <hip/hip_runtime.h>
#include <math.h>

namespace {

constexpr int B = 16, H = 512, W = 512;
constexpr int HWc = H * W;                 // 262144
constexpr size_t Nc = (size_t)B * HWc;     // 4194304

// Strip geometry: 64-lane wave holds cols [strip*42-11, strip*42+52].
// Boundary stencil (3x3) corrupts lanes 0,63; each of the 10 dilation steps
// corrupts one more lane per side -> valid central lanes 11..52 = 42 cols.
// 13 strips x 42 = 546 >= 512 (mask col < 512). Exact tiling, no overlap.
constexpr int NSTRIP = 13;
constexpr int CENT = 42;
constexpr int NBAND = 16;  // 512 / 32 rows
constexpr int NWORK = NSTRIP * NBAND * B * 2;  // 6656 wave work items
constexpr int NP = NSTRIP * NBAND * B;         // 3328 CH0-wave partials

// ---------------- DPP lane shifts ----------------
// wave_shr:1 (0x138): lane i <- lane i-1 (lane 0 keeps own -> replicate edge)
// wave_shl:1 (0x130): lane i <- lane i+1 (lane 63 keeps own)
template <int CTRL>
__device__ __forceinline__ float dpp_shift1(float v) {
  int i = __float_as_int(v);
  int r = __builtin_amdgcn_update_dpp(i, i, CTRL, 0xF, 0xF, false);
  return __int_as_float(r);
}

// R4 post-mortem: measured dynamic instr/wave (~8.5k) is ~1.7x the hand count
// assuming 3-way max trees fuse to v_max3_f32. Force the fusion via inline
// asm (no portable builtin; T17). Non-volatile asm: scheduler may reorder.
__device__ __forceinline__ float max3f(float a, float b, float c) {
  float d;
  asm("v_max3_f32 %0, %1, %2, %3" : "=v"(d) : "v"(a), "v"(b), "v"(c));
  return d;
}
__device__ __forceinline__ float min3f(float a, float b, float c) {
  float d;
  asm("v_min3_f32 %0, %1, %2, %3" : "=v"(d) : "v"(a), "v"(b), "v"(c));
  return d;
}

__device__ __forceinline__ float hmax3(float v) {
  return max3f(dpp_shift1<0x138>(v), v, dpp_shift1<0x130>(v));
}
__device__ __forceinline__ float hmin3(float v) {
  return min3f(dpp_shift1<0x138>(v), v, dpp_shift1<0x130>(v));
}

__device__ __forceinline__ float wave_sum(float v) {
#pragma unroll
  for (int off = 32; off > 0; off >>= 1) v += __shfl_down(v, off);
  return v;
}

// --- block-wide sum over 256 threads (4 waves of 64). Valid on tid==0 only.
__device__ __forceinline__ float block_reduce_256(float v, float* sm, int tid) {
#pragma unroll
  for (int off = 32; off > 0; off >>= 1) v += __shfl_down(v, off);
  int lane = tid & 63, wid = tid >> 6;
  if (lane == 0) sm[wid] = v;
  __syncthreads();
  float r = 0.f;
  if (tid == 0) r = sm[0] + sm[1] + sm[2] + sm[3];
  __syncthreads();
  return r;
}

// CH==0: src map = sigmoid(logits), oth map = target.
// CH==1: src map = target,          oth map = sigmoid(logits).
// EDGE: row clamp needed only for bands 0 and 15.
template <int CH, bool EDGE>
__device__ __forceinline__ float load_src(const float* __restrict__ Lg,
                                          const int* __restrict__ Tg, int gy,
                                          int colc) {
  if constexpr (EDGE) gy = min(max(gy, 0), H - 1);
  if constexpr (CH == 0) {
    float x = Lg[gy * W + colc];
    float e = __expf(-x);
    return __builtin_amdgcn_rcpf(1.f + e);
  } else {
    return (float)Tg[gy * W + colc];
  }
}

// ---- dilation steps via template recursion (R2: compile-time D keeps all
// indices constant -> arrays stay register-resident).
// R4: acc split 4 ways -- the single acc was a 320-deep dependent FMA chain
// (4 cyc each = 1280 cyc pure latency/wave); 4 accumulators cut depth to 80.
template <int D>
__device__ __forceinline__ void dilate_steps(float (&a)[52],
                                             const float (&o)[32],
                                             float (&accv)[4]) {
  if constexpr (D <= 10) {
    float hp = hmax3(a[D - 1]);
    float hc = hmax3(a[D]);
#pragma unroll
    for (int r = D; r <= 51 - D; ++r) {  // trip count 52-2D: compile-time
      float hn = hmax3(a[r + 1]);
      float nv = max3f(hp, hc, hn);
      hp = hc;
      hc = hn;
      a[r] = nv;
    }
    constexpr float wd = 0.1f * (float)D;
#pragma unroll
    for (int k = 0; k < 32; ++k) accv[k & 3] += wd * fabsf(a[10 + k] - o[k]);
    dilate_steps<D + 1>(a, o, accv);
  }
}

// ---------------- fused: everything in one kernel ---------------------------
// One wave per (strip, band, img, chain). Boundary maps never hit global:
// 3x3 dil-ero via DPP horizontal max3/min3 + rolling vertical registers.
// CH0 waves additionally compute BCE/dice/tversky partials over their central
// 42x32 region (exact tiling of the image): R5 re-fold -- as a separate
// streaming kernel it cost ~6 us serially on the stream; here it's ~450 extra
// VALU instr on half the waves, with all loads L1-hot.
template <int CH, bool EDGE>
__device__ __forceinline__ void fused_body(
    const float* __restrict__ Lg, const int* __restrict__ Tg, int lane,
    int strip, int band, int img, int bz, float* __restrict__ bce_p,
    float* __restrict__ sp_p, float* __restrict__ st_p,
    float* __restrict__ spt_p, float* __restrict__ chain_p) {
  int col = strip * CENT - 11 + lane;
  int colc = min(max(col, 0), W - 1);
  int y0 = band * 32;
  bool valid = (lane >= 11 && lane <= 52 && col < W);

  // ---- BCE + dice partials (CH0 only, central rows: never need row clamp).
  // Identity: max(x,0) - x*t + log1p(exp(-|x|)) == x*(1-t) + log(1+e^-x).
  if constexpr (CH == 0) {
    float s_bce = 0.f, s_p = 0.f, s_t = 0.f, s_pt = 0.f;
#pragma unroll
    for (int k = 0; k < 32; ++k) {
      float x = Lg[(y0 + k) * W + colc];
      float tf = (float)Tg[(y0 + k) * W + colc];
      float e = __expf(-x);
      float p = __builtin_amdgcn_rcpf(1.f + e);
      s_p += p;
      s_t += tf;
      s_pt += p * tf;
      s_bce += x * (1.f - tf) + __logf(1.f + e);
    }
    if (!valid) {
      s_bce = 0.f;
      s_p = 0.f;
      s_t = 0.f;
      s_pt = 0.f;
    }
    s_bce = wave_sum(s_bce);
    s_p = wave_sum(s_p);
    s_t = wave_sum(s_t);
    s_pt = wave_sum(s_pt);
    if (lane == 0) {
      int pi = (img * NBAND + band) * NSTRIP + strip;
      bce_p[pi] = s_bce;
      sp_p[pi] = s_p;
      st_p[pi] = s_t;
      spt_p[pi] = s_pt;
    }
  }

  // ---- other-map boundary, central rows y0..y0+31 (rolling 3-row stencil)
  float o[32];
  {
    float v0 = load_src<1 - CH, EDGE>(Lg, Tg, y0 - 1, colc);
    float v1 = load_src<1 - CH, EDGE>(Lg, Tg, y0, colc);
    float hx0 = hmax3(v0), hn0 = hmin3(v0);
    float hx1 = hmax3(v1), hn1 = hmin3(v1);
#pragma unroll
    for (int k = 0; k < 32; ++k) {
      float v2 = load_src<1 - CH, EDGE>(Lg, Tg, y0 + 1 + k, colc);
      float hx2 = hmax3(v2), hn2 = hmin3(v2);
      o[k] = max3f(hx0, hx1, hx2) - min3f(hn0, hn1, hn2);
      hx0 = hx1;
      hx1 = hx2;
      hn0 = hn1;
      hn1 = hn2;
    }
  }

  // ---- src-map boundary incl. vertical halo: rows y0-10 .. y0+41
  float a[52];
  {
    float v0 = load_src<CH, EDGE>(Lg, Tg, y0 - 11, colc);
    float v1 = load_src<CH, EDGE>(Lg, Tg, y0 - 10, colc);
    float hx0 = hmax3(v0), hn0 = hmin3(v0);
    float hx1 = hmax3(v1), hn1 = hmin3(v1);
#pragma unroll
    for (int r = 0; r < 52; ++r) {
      float v2 = load_src<CH, EDGE>(Lg, Tg, y0 - 9 + r, colc);
      float hx2 = hmax3(v2), hn2 = hmin3(v2);
      a[r] = max3f(hx0, hx1, hx2) - min3f(hn0, hn1, hn2);
      hx0 = hx1;
      hx1 = hx2;
      hn0 = hn1;
      hn1 = hn2;
    }
  }

  // ---- 10-step register-resident dilation + weighted L1 accumulation
  float accv[4] = {0.f, 0.f, 0.f, 0.f};
  dilate_steps<1>(a, o, accv);
  float acc = (accv[0] + accv[1]) + (accv[2] + accv[3]);

  acc = valid ? acc : 0.f;
  acc = wave_sum(acc);
  if (lane == 0) chain_p[(bz * NBAND + band) * NSTRIP + strip] = acc;
}

// 256-thread blocks, 4 independent waves each. __launch_bounds__(256, 4) =>
// 128-reg/thread budget (unified VGPR+AGPR file on gfx950) so a[52]+o[32]+
// rolling temps stay register-resident (R3: scratch eliminated).
__global__ void __launch_bounds__(256, 4) fused_kernel(
    const float* __restrict__ logits, const int* __restrict__ target,
    float* __restrict__ bce_p, float* __restrict__ sp_p,
    float* __restrict__ st_p, float* __restrict__ spt_p,
    float* __restrict__ chain_p) {
  int tid = threadIdx.x;
  int lane = tid & 63;
  int wv = tid >> 6;
  int widx = blockIdx.x * 4 + wv;  // 0..6655, exact (NWORK/4 blocks)
  int strip = widx % NSTRIP;
  int rest = widx / NSTRIP;
  int band = rest & 15;
  int bz = rest >> 4;  // 0..31
  int img = bz & 15, chain = bz >> 4;
  const float* Lg = logits + (size_t)img * HWc;
  const int* Tg = target + (size_t)img * HWc;
  bool edge = (band == 0) | (band == 15);
  if (chain == 0) {
    if (edge)
      fused_body<0, true>(Lg, Tg, lane, strip, band, img, bz, bce_p, sp_p,
                          st_p, spt_p, chain_p);
    else
      fused_body<0, false>(Lg, Tg, lane, strip, band, img, bz, bce_p, sp_p,
                           st_p, spt_p, chain_p);
  } else {
    if (edge)
      fused_body<1, true>(Lg, Tg, lane, strip, band, img, bz, bce_p, sp_p,
                          st_p, spt_p, chain_p);
    else
      fused_body<1, false>(Lg, Tg, lane, strip, band, img, bz, bce_p, sp_p,
                           st_p, spt_p, chain_p);
  }
}

// ---------------- finalize ----------------
__global__ void finalize_kernel(const float* __restrict__ bce_p,
                                const float* __restrict__ sp_p,
                                const float* __restrict__ st_p,
                                const float* __restrict__ spt_p,
                                const float* __restrict__ chain_p,
                                float* __restrict__ out) {
  __shared__ float smr[4];
  __shared__ float smImg[16][3];
  __shared__ double smd[16][2];
  int tid = threadIdx.x;

  float s = 0.f;
  for (int i = tid; i < NP; i += 256) s += bce_p[i];  // 3328
  float bce_sum = block_reduce_256(s, smr, tid);

  s = 0.f;
  for (int i = tid; i < NWORK; i += 256) s += chain_p[i];  // 6656
  float hd_sum = block_reduce_256(s, smr, tid);

  {
    int img = tid >> 4, part = tid & 15;  // 16 threads per image
    float sp = 0.f, st = 0.f, spt = 0.f;
    for (int j = part; j < NBAND * NSTRIP; j += 16) {  // 208/image, 13 iters
      int idx = img * (NBAND * NSTRIP) + j;
      sp += sp_p[idx];
      st += st_p[idx];
      spt += spt_p[idx];
    }
#pragma unroll
    for (int off = 8; off > 0; off >>= 1) {
      sp += __shfl_down(sp, off, 16);
      st += __shfl_down(st, off, 16);
      spt += __shfl_down(spt, off, 16);
    }
    if (part == 0) {
      smImg[img][0] = sp;
      smImg[img][1] = st;
      smImg[img][2] = spt;
    }
  }
  __syncthreads();
  if (tid < 16) {
    double sp = smImg[tid][0], st = smImg[tid][1], spt = smImg[tid][2];
    double dice = (2.0 * spt + 1e-6) / (sp + st + 1e-6 + 1e-7);
    double tv = (spt + 1e-6) /
                (spt + 0.7 * (sp - spt) + 0.3 * (st - spt) + 1e-6 + 1e-7);
    smd[tid][0] = 1.0 - dice;
    smd[tid][1] = pow(1.0 - tv, 0.75);
  }
  __syncthreads();
  if (tid == 0) {
    double dice_l = 0.0, ft_l = 0.0;
    for (int i = 0; i < 16; ++i) {
      dice_l += smd[i][0];
      ft_l += smd[i][1];
    }
    dice_l /= 16.0;
    ft_l /= 16.0;
    const double Nd = (double)Nc;
    double bce = (double)bce_sum / Nd;
    double hd = ((double)hd_sum / Nd) / (5.5 + 1e-8);
    out[0] = (float)(bce + dice_l + ft_l + 0.1 * hd);
  }
}

}  // namespace

extern "C" void kernel_launch(void* const* d_in, const int* in_sizes, int n_in,
                              void* d_out, int out_size, void* d_ws,
                              size_t ws_size, hipStream_t stream) {
  const float* logits = (const float*)d_in[0];
  const int* target = (const int*)d_in[1];
  float* out = (float*)d_out;

  // Workspace: only small partial arrays (boundary maps never hit global).
  // All slots below are fully written each launch.
  float* part = (float*)d_ws;
  float* bce_p = part;               // 3328 = 16*16*13 (CH0 waves)
  float* sp_p = part + NP;           // 3328
  float* st_p = part + 2 * NP;       // 3328
  float* spt_p = part + 3 * NP;      // 3328
  float* chain_p = part + 4 * NP;    // 6656 = 32*16*13

  fused_kernel<<<dim3(NWORK / 4), dim3(256), 0, stream>>>(
      logits, target, bce_p, sp_p, st_p, spt_p, chain_p);
  finalize_kernel<<<1, 256, 0, stream>>>(bce_p, sp_p, st_p, spt_p, chain_p,
                                         out);
}

// Round 6
// 139.163 us; speedup vs baseline: 3.3386x; 3.3386x over previous
//
#include <hip/hip_runtime.h>
#include <math.h>

namespace {

constexpr int B = 16, H = 512, W = 512;
constexpr int HWc = H * W;                 // 262144
constexpr size_t Nc = (size_t)B * HWc;     // 4194304

// Strip geometry: 64-lane wave holds cols [strip*42-11, strip*42+52].
// Boundary stencil (3x3) corrupts lanes 0,63; each of the 10 dilation steps
// corrupts one more lane per side -> valid central lanes 11..52 = 42 cols.
// 13 strips x 42 = 546 >= 512 (mask col < 512). Exact tiling, no overlap.
constexpr int NSTRIP = 13;
constexpr int CENT = 42;
constexpr int NBAND = 16;  // 512 / 32 rows
constexpr int NWORK = NSTRIP * NBAND * B * 2;  // 6656 wave work items
constexpr int NSB = NWORK / 4;                 // 1664 stencil blocks
constexpr int NBCE = B * 64;                   // 1024 bce partial blocks

// ---------------- DPP lane shifts ----------------
// wave_shr:1 (0x138): lane i <- lane i-1 (lane 0 keeps own -> replicate edge)
// wave_shl:1 (0x130): lane i <- lane i+1 (lane 63 keeps own)
template <int CTRL>
__device__ __forceinline__ float dpp_shift1(float v) {
  int i = __float_as_int(v);
  int r = __builtin_amdgcn_update_dpp(i, i, CTRL, 0xF, 0xF, false);
  return __int_as_float(r);
}

// R5 post-mortem: inline-asm v_max3_f32 with "v" constraints forced the whole
// live set into the VGPR half of the unified file (asm can't touch AGPRs) ->
// a[52]+o[32] spilled to scratch (539 MB WRITE_SIZE, 411 us, VALUBusy 12%).
// Plain fmaxf/fminf trees: clang fuses them to v_max3/v_min3 on its own and
// the allocator keeps arrays in AGPRs (R3/R4: VGPR_Count 56-60, zero spill).
__device__ __forceinline__ float hmax3(float v) {
  return fmaxf(fmaxf(dpp_shift1<0x138>(v), v), dpp_shift1<0x130>(v));
}
__device__ __forceinline__ float hmin3(float v) {
  return fminf(fminf(dpp_shift1<0x138>(v), v), dpp_shift1<0x130>(v));
}

__device__ __forceinline__ float wave_sum(float v) {
#pragma unroll
  for (int off = 32; off > 0; off >>= 1) v += __shfl_down(v, off);
  return v;
}

// --- block-wide sum over 256 threads (4 waves of 64). Valid on tid==0 only.
__device__ __forceinline__ float block_reduce_256(float v, float* sm, int tid) {
#pragma unroll
  for (int off = 32; off > 0; off >>= 1) v += __shfl_down(v, off);
  int lane = tid & 63, wid = tid >> 6;
  if (lane == 0) sm[wid] = v;
  __syncthreads();
  float r = 0.f;
  if (tid == 0) r = sm[0] + sm[1] + sm[2] + sm[3];
  __syncthreads();
  return r;
}

// CH==0: src map = sigmoid(logits), oth map = target.
// CH==1: src map = target,          oth map = sigmoid(logits).
// EDGE: row clamp needed only for bands 0 and 15.
template <int CH, bool EDGE>
__device__ __forceinline__ float load_src(const float* __restrict__ Lg,
                                          const int* __restrict__ Tg, int gy,
                                          int colc) {
  if constexpr (EDGE) gy = min(max(gy, 0), H - 1);
  if constexpr (CH == 0) {
    float x = Lg[gy * W + colc];
    float e = __expf(-x);
    return __builtin_amdgcn_rcpf(1.f + e);
  } else {
    return (float)Tg[gy * W + colc];
  }
}

// ---- dilation steps via template recursion (R2: compile-time D keeps all
// indices constant -> arrays stay register-resident).
// R4/R5: acc split 4 ways -- single acc was a 320-deep dependent FMA chain;
// 4 accumulators cut latency depth to 80 (3 extra regs, safe).
template <int D>
__device__ __forceinline__ void dilate_steps(float (&a)[52],
                                             const float (&o)[32],
                                             float (&accv)[4]) {
  if constexpr (D <= 10) {
    float hp = hmax3(a[D - 1]);
    float hc = hmax3(a[D]);
#pragma unroll
    for (int r = D; r <= 51 - D; ++r) {  // trip count 52-2D: compile-time
      float hn = hmax3(a[r + 1]);
      float nv = fmaxf(fmaxf(hp, hc), hn);
      hp = hc;
      hc = hn;
      a[r] = nv;
    }
    constexpr float wd = 0.1f * (float)D;
#pragma unroll
    for (int k = 0; k < 32; ++k) accv[k & 3] += wd * fabsf(a[10 + k] - o[k]);
    dilate_steps<D + 1>(a, o, accv);
  }
}

// ---------------- stencil wave body (R4-proven) -----------------------------
// One wave per (strip, band, img, chain). Boundary maps never hit global:
// 3x3 dil-ero via DPP horizontal max/min + rolling vertical registers.
template <int CH, bool EDGE>
__device__ __forceinline__ void fused_body(const float* __restrict__ Lg,
                                           const int* __restrict__ Tg,
                                           int lane, int strip, int band,
                                           int bz,
                                           float* __restrict__ chain_p) {
  int col = strip * CENT - 11 + lane;
  int colc = min(max(col, 0), W - 1);
  int y0 = band * 32;

  // ---- other-map boundary, central rows y0..y0+31 (rolling 3-row stencil)
  float o[32];
  {
    float v0 = load_src<1 - CH, EDGE>(Lg, Tg, y0 - 1, colc);
    float v1 = load_src<1 - CH, EDGE>(Lg, Tg, y0, colc);
    float hx0 = hmax3(v0), hn0 = hmin3(v0);
    float hx1 = hmax3(v1), hn1 = hmin3(v1);
#pragma unroll
    for (int k = 0; k < 32; ++k) {
      float v2 = load_src<1 - CH, EDGE>(Lg, Tg, y0 + 1 + k, colc);
      float hx2 = hmax3(v2), hn2 = hmin3(v2);
      o[k] = fmaxf(fmaxf(hx0, hx1), hx2) - fminf(fminf(hn0, hn1), hn2);
      hx0 = hx1;
      hx1 = hx2;
      hn0 = hn1;
      hn1 = hn2;
    }
  }

  // ---- src-map boundary incl. vertical halo: rows y0-10 .. y0+41
  float a[52];
  {
    float v0 = load_src<CH, EDGE>(Lg, Tg, y0 - 11, colc);
    float v1 = load_src<CH, EDGE>(Lg, Tg, y0 - 10, colc);
    float hx0 = hmax3(v0), hn0 = hmin3(v0);
    float hx1 = hmax3(v1), hn1 = hmin3(v1);
#pragma unroll
    for (int r = 0; r < 52; ++r) {
      float v2 = load_src<CH, EDGE>(Lg, Tg, y0 - 9 + r, colc);
      float hx2 = hmax3(v2), hn2 = hmin3(v2);
      a[r] = fmaxf(fmaxf(hx0, hx1), hx2) - fminf(fminf(hn0, hn1), hn2);
      hx0 = hx1;
      hx1 = hx2;
      hn0 = hn1;
      hn1 = hn2;
    }
  }

  // ---- 10-step register-resident dilation + weighted L1 accumulation
  float accv[4] = {0.f, 0.f, 0.f, 0.f};
  dilate_steps<1>(a, o, accv);
  float acc = (accv[0] + accv[1]) + (accv[2] + accv[3]);

  bool valid = (lane >= 11 && lane <= 52 && col < W);
  acc = valid ? acc : 0.f;
  acc = wave_sum(acc);
  if (lane == 0) chain_p[(bz * NBAND + band) * NSTRIP + strip] = acc;
}

// ---------------- BCE block body (R4's bce_kernel, now merged) --------------
// Identity: max(x,0) - x*t + log1p(exp(-|x|)) == x*(1-t) + log(1+e^-x).
__device__ __forceinline__ void bce_body(const float* __restrict__ logits,
                                         const int* __restrict__ target,
                                         int blk, float* __restrict__ bceA,
                                         float* __restrict__ spA,
                                         float* __restrict__ stA,
                                         float* __restrict__ sptA) {
  __shared__ float smr[4];
  int img = blk >> 6, seg = blk & 63;  // 64 blocks/image
  const float4* L4 =
      (const float4*)(logits + (size_t)img * HWc + (size_t)seg * 4096);
  const int4* T4 =
      (const int4*)(target + (size_t)img * HWc + (size_t)seg * 4096);
  int tid = threadIdx.x;
  float s_bce = 0.f, s_p = 0.f, s_t = 0.f, s_pt = 0.f;
#pragma unroll
  for (int it = 0; it < 4; ++it) {
    float4 x4 = L4[it * 256 + tid];
    int4 t4 = T4[it * 256 + tid];
    float xs[4] = {x4.x, x4.y, x4.z, x4.w};
    int ts[4] = {t4.x, t4.y, t4.z, t4.w};
#pragma unroll
    for (int j = 0; j < 4; ++j) {
      float x = xs[j];
      float tf = (float)ts[j];
      float e = __expf(-x);
      float p = __builtin_amdgcn_rcpf(1.f + e);
      s_p += p;
      s_t += tf;
      s_pt += p * tf;
      s_bce += x * (1.f - tf) + __logf(1.f + e);
    }
  }
  float r;
  r = block_reduce_256(s_bce, smr, tid);
  if (tid == 0) bceA[blk] = r;
  r = block_reduce_256(s_p, smr, tid);
  if (tid == 0) spA[blk] = r;
  r = block_reduce_256(s_t, smr, tid);
  if (tid == 0) stA[blk] = r;
  r = block_reduce_256(s_pt, smr, tid);
  if (tid == 0) sptA[blk] = r;
}

// ---------------- merged kernel ---------------------------------------------
// Heterogeneous blocks: first NBCE blocks stream BCE/dice partials (memory-
// bound), remaining NSB blocks run the stencil (VALU-bound). Dispatching the
// memory-bound blocks first lets them overlap with stencil compute instead of
// serializing as a separate ~6 us launch (R4 structure, one dispatch fewer).
// __launch_bounds__(256, 4): proven R3/R4 shape -- keeps stencil arrays
// register-resident (unified VGPR+AGPR file).
__global__ void __launch_bounds__(256, 4) fused_kernel(
    const float* __restrict__ logits, const int* __restrict__ target,
    float* __restrict__ bceA, float* __restrict__ spA,
    float* __restrict__ stA, float* __restrict__ sptA,
    float* __restrict__ chain_p) {
  if (blockIdx.x < NBCE) {
    bce_body(logits, target, blockIdx.x, bceA, spA, stA, sptA);
    return;
  }
  int tid = threadIdx.x;
  int lane = tid & 63;
  int wv = tid >> 6;
  int widx = (blockIdx.x - NBCE) * 4 + wv;  // 0..6655, exact
  int strip = widx % NSTRIP;
  int rest = widx / NSTRIP;
  int band = rest & 15;
  int bz = rest >> 4;  // 0..31
  int img = bz & 15, chain = bz >> 4;
  const float* Lg = logits + (size_t)img * HWc;
  const int* Tg = target + (size_t)img * HWc;
  bool edge = (band == 0) | (band == 15);
  if (chain == 0) {
    if (edge)
      fused_body<0, true>(Lg, Tg, lane, strip, band, bz, chain_p);
    else
      fused_body<0, false>(Lg, Tg, lane, strip, band, bz, chain_p);
  } else {
    if (edge)
      fused_body<1, true>(Lg, Tg, lane, strip, band, bz, chain_p);
    else
      fused_body<1, false>(Lg, Tg, lane, strip, band, bz, chain_p);
  }
}

// ---------------- finalize ----------------
__global__ void finalize_kernel(const float* __restrict__ bceA,
                                const float* __restrict__ spA,
                                const float* __restrict__ stA,
                                const float* __restrict__ sptA,
                                const float* __restrict__ chain_p,
                                float* __restrict__ out) {
  __shared__ float smr[4];
  __shared__ float smImg[16][3];
  __shared__ double smd[16][2];
  int tid = threadIdx.x;

  float s = 0.f;
  for (int i = tid; i < NBCE; i += 256) s += bceA[i];  // 1024
  float bce_sum = block_reduce_256(s, smr, tid);

  s = 0.f;
  for (int i = tid; i < NWORK; i += 256) s += chain_p[i];  // 6656
  float hd_sum = block_reduce_256(s, smr, tid);

  {
    int img = tid >> 4, part = tid & 15;  // 16 threads per image
    float sp = 0.f, st = 0.f, spt = 0.f;
    for (int j = part; j < 64; j += 16) {  // 64 partials/image, 4 iters
      int idx = img * 64 + j;
      sp += spA[idx];
      st += stA[idx];
      spt += sptA[idx];
    }
#pragma unroll
    for (int off = 8; off > 0; off >>= 1) {
      sp += __shfl_down(sp, off, 16);
      st += __shfl_down(st, off, 16);
      spt += __shfl_down(spt, off, 16);
    }
    if (part == 0) {
      smImg[img][0] = sp;
      smImg[img][1] = st;
      smImg[img][2] = spt;
    }
  }
  __syncthreads();
  if (tid < 16) {
    double sp = smImg[tid][0], st = smImg[tid][1], spt = smImg[tid][2];
    double dice = (2.0 * spt + 1e-6) / (sp + st + 1e-6 + 1e-7);
    double tv = (spt + 1e-6) /
                (spt + 0.7 * (sp - spt) + 0.3 * (st - spt) + 1e-6 + 1e-7);
    smd[tid][0] = 1.0 - dice;
    smd[tid][1] = pow(1.0 - tv, 0.75);
  }
  __syncthreads();
  if (tid == 0) {
    double dice_l = 0.0, ft_l = 0.0;
    for (int i = 0; i < 16; ++i) {
      dice_l += smd[i][0];
      ft_l += smd[i][1];
    }
    dice_l /= 16.0;
    ft_l /= 16.0;
    const double Nd = (double)Nc;
    double bce = (double)bce_sum / Nd;
    double hd = ((double)hd_sum / Nd) / (5.5 + 1e-8);
    out[0] = (float)(bce + dice_l + ft_l + 0.1 * hd);
  }
}

}  // namespace

extern "C" void kernel_launch(void* const* d_in, const int* in_sizes, int n_in,
                              void* d_out, int out_size, void* d_ws,
                              size_t ws_size, hipStream_t stream) {
  const float* logits = (const float*)d_in[0];
  const int* target = (const int*)d_in[1];
  float* out = (float*)d_out;

  // Workspace: only small partial arrays (boundary maps never hit global).
  // All slots below are fully written each launch.
  float* part = (float*)d_ws;
  float* bceA = part;                  // 1024
  float* spA = part + NBCE;            // 1024
  float* stA = part + 2 * NBCE;        // 1024
  float* sptA = part + 3 * NBCE;       // 1024
  float* chain_p = part + 4 * NBCE;    // 6656 = 32*16*13

  fused_kernel<<<dim3(NBCE + NSB), dim3(256), 0, stream>>>(
      logits, target, bceA, spA, stA, sptA, chain_p);
  finalize_kernel<<<1, 256, 0, stream>>>(bceA, spA, stA, sptA, chain_p, out);
}

// Round 7
// 136.591 us; speedup vs baseline: 3.4015x; 1.0188x over previous
//
#include <hip/hip_runtime.h>
#include <math.h>

namespace {

constexpr int B = 16, H = 512, W = 512;
constexpr int HWc = H * W;                 // 262144
constexpr size_t Nc = (size_t)B * HWc;     // 4194304

// Strip geometry: 64-lane wave holds cols [strip*42-11, strip*42+52].
// Boundary stencil (3x3) corrupts lanes 0,63; each of the 10 dilation steps
// corrupts one more lane per side -> valid central lanes 11..52 = 42 cols.
// 13 strips x 42 = 546 >= 512 (mask col < 512). Exact tiling, no overlap.
constexpr int NSTRIP = 13;
constexpr int CENT = 42;
constexpr int NBAND = 16;  // 512 / 32 rows
constexpr int NWORK = NSTRIP * NBAND * B * 2;  // 6656 wave work items
constexpr int NSB = NWORK / 4;                 // 1664 stencil blocks
constexpr int NBCE = B * 64;                   // 1024 bce partial blocks

// ---------------- DPP lane shifts ----------------
// wave_shr:1 (0x138): lane i <- lane i-1 (lane 0 keeps own -> replicate edge)
// wave_shl:1 (0x130): lane i <- lane i+1 (lane 63 keeps own)
template <int CTRL>
__device__ __forceinline__ float dpp_shift1(float v) {
  int i = __float_as_int(v);
  int r = __builtin_amdgcn_update_dpp(i, i, CTRL, 0xF, 0xF, false);
  return __int_as_float(r);
}

// R5 post-mortem: NO inline-asm max3 -- asm "v" constraints pin the live set
// to the VGPR half of the unified file and a[52]+o[32] spill (539 MB scratch,
// 411 us). Plain fmaxf/fminf trees: clang fuses to v_max3/v_min3 itself and
// the allocator parks arrays in AGPRs (R3/R4/R6: VGPR_Count 56-60, no spill).
__device__ __forceinline__ float hmax3(float v) {
  return fmaxf(fmaxf(dpp_shift1<0x138>(v), v), dpp_shift1<0x130>(v));
}
// Boundary builds need max AND min of the same 3 lanes: share the two DPP
// shifts explicitly (guaranteed CSE; 2 fewer DPP movs per boundary row).
__device__ __forceinline__ void hminmax3(float v, float& mx, float& mn) {
  float s1 = dpp_shift1<0x138>(v);
  float s2 = dpp_shift1<0x130>(v);
  mx = fmaxf(fmaxf(s1, v), s2);
  mn = fminf(fminf(s1, v), s2);
}

__device__ __forceinline__ float wave_sum(float v) {
#pragma unroll
  for (int off = 32; off > 0; off >>= 1) v += __shfl_down(v, off);
  return v;
}

// --- block-wide sum over 256 threads (4 waves of 64). Valid on tid==0 only.
__device__ __forceinline__ float block_reduce_256(float v, float* sm, int tid) {
#pragma unroll
  for (int off = 32; off > 0; off >>= 1) v += __shfl_down(v, off);
  int lane = tid & 63, wid = tid >> 6;
  if (lane == 0) sm[wid] = v;
  __syncthreads();
  float r = 0.f;
  if (tid == 0) r = sm[0] + sm[1] + sm[2] + sm[3];
  __syncthreads();
  return r;
}

// CH==0: src map = sigmoid(logits), oth map = target.
// CH==1: src map = target,          oth map = sigmoid(logits).
// gy is WAVE-UNIFORM (scalar after readfirstlane): the clamp and row-base
// arithmetic are SALU, loads are [SGPR rowbase + VGPR col] saddr form.
// R6 post-mortem: previously wv=tid>>6 was thread-varying to the compiler,
// so band/strip/img/chain/y0 and the image base pointers were all VGPRs ->
// full vector 64-bit address math on every one of ~120 unrolled loads.
template <int CH>
__device__ __forceinline__ float load_src(const float* __restrict__ Lg,
                                          const int* __restrict__ Tg, int gy,
                                          int colc) {
  gy = min(max(gy, 0), H - 1);  // scalar clamp: makes EDGE templating free
  if constexpr (CH == 0) {
    float x = Lg[gy * W + colc];
    float e = __expf(-x);
    return __builtin_amdgcn_rcpf(1.f + e);
  } else {
    return (float)Tg[gy * W + colc];
  }
}

// ---- dilation steps via template recursion (R2: compile-time D keeps all
// indices constant -> arrays stay register-resident).
// R4: acc split 4 ways -- single acc was a 320-deep dependent FMA chain;
// 4 accumulators cut latency depth to 80.
template <int D>
__device__ __forceinline__ void dilate_steps(float (&a)[52],
                                             const float (&o)[32],
                                             float (&accv)[4]) {
  if constexpr (D <= 10) {
    float hp = hmax3(a[D - 1]);
    float hc = hmax3(a[D]);
#pragma unroll
    for (int r = D; r <= 51 - D; ++r) {  // trip count 52-2D: compile-time
      float hn = hmax3(a[r + 1]);
      float nv = fmaxf(fmaxf(hp, hc), hn);
      hp = hc;
      hc = hn;
      a[r] = nv;
    }
    constexpr float wd = 0.1f * (float)D;
#pragma unroll
    for (int k = 0; k < 32; ++k) accv[k & 3] += wd * fabsf(a[10 + k] - o[k]);
    dilate_steps<D + 1>(a, o, accv);
  }
}

// ---------------- stencil wave body -----------------------------------------
// One wave per (strip, band, img, chain). Boundary maps never hit global:
// 3x3 dil-ero via DPP horizontal max/min + rolling vertical registers.
// All of strip/band/bz/y0 are scalar (readfirstlane'd upstream).
template <int CH>
__device__ __forceinline__ void fused_body(const float* __restrict__ Lg,
                                           const int* __restrict__ Tg,
                                           int lane, int strip, int band,
                                           int bz,
                                           float* __restrict__ chain_p) {
  int col = strip * CENT - 11 + lane;
  int colc = min(max(col, 0), W - 1);
  int y0 = band * 32;

  // ---- other-map boundary, central rows y0..y0+31 (rolling 3-row stencil)
  float o[32];
  {
    float v0 = load_src<1 - CH>(Lg, Tg, y0 - 1, colc);
    float v1 = load_src<1 - CH>(Lg, Tg, y0, colc);
    float hx0, hn0, hx1, hn1;
    hminmax3(v0, hx0, hn0);
    hminmax3(v1, hx1, hn1);
#pragma unroll
    for (int k = 0; k < 32; ++k) {
      float v2 = load_src<1 - CH>(Lg, Tg, y0 + 1 + k, colc);
      float hx2, hn2;
      hminmax3(v2, hx2, hn2);
      o[k] = fmaxf(fmaxf(hx0, hx1), hx2) - fminf(fminf(hn0, hn1), hn2);
      hx0 = hx1;
      hx1 = hx2;
      hn0 = hn1;
      hn1 = hn2;
    }
  }

  // ---- src-map boundary incl. vertical halo: rows y0-10 .. y0+41
  float a[52];
  {
    float v0 = load_src<CH>(Lg, Tg, y0 - 11, colc);
    float v1 = load_src<CH>(Lg, Tg, y0 - 10, colc);
    float hx0, hn0, hx1, hn1;
    hminmax3(v0, hx0, hn0);
    hminmax3(v1, hx1, hn1);
#pragma unroll
    for (int r = 0; r < 52; ++r) {
      float v2 = load_src<CH>(Lg, Tg, y0 - 9 + r, colc);
      float hx2, hn2;
      hminmax3(v2, hx2, hn2);
      a[r] = fmaxf(fmaxf(hx0, hx1), hx2) - fminf(fminf(hn0, hn1), hn2);
      hx0 = hx1;
      hx1 = hx2;
      hn0 = hn1;
      hn1 = hn2;
    }
  }

  // ---- 10-step register-resident dilation + weighted L1 accumulation
  float accv[4] = {0.f, 0.f, 0.f, 0.f};
  dilate_steps<1>(a, o, accv);
  float acc = (accv[0] + accv[1]) + (accv[2] + accv[3]);

  bool valid = (lane >= 11 && lane <= 52 && col < W);
  acc = valid ? acc : 0.f;
  acc = wave_sum(acc);
  if (lane == 0) chain_p[(bz * NBAND + band) * NSTRIP + strip] = acc;
}

// ---------------- BCE block body --------------------------------------------
// Identity: max(x,0) - x*t + log1p(exp(-|x|)) == x*(1-t) + log(1+e^-x).
__device__ __forceinline__ void bce_body(const float* __restrict__ logits,
                                         const int* __restrict__ target,
                                         int blk, float* __restrict__ bceA,
                                         float* __restrict__ spA,
                                         float* __restrict__ stA,
                                         float* __restrict__ sptA) {
  __shared__ float smr[4];
  int img = blk >> 6, seg = blk & 63;  // 64 blocks/image
  const float4* L4 =
      (const float4*)(logits + (size_t)img * HWc + (size_t)seg * 4096);
  const int4* T4 =
      (const int4*)(target + (size_t)img * HWc + (size_t)seg * 4096);
  int tid = threadIdx.x;
  float s_bce = 0.f, s_p = 0.f, s_t = 0.f, s_pt = 0.f;
#pragma unroll
  for (int it = 0; it < 4; ++it) {
    float4 x4 = L4[it * 256 + tid];
    int4 t4 = T4[it * 256 + tid];
    float xs[4] = {x4.x, x4.y, x4.z, x4.w};
    int ts[4] = {t4.x, t4.y, t4.z, t4.w};
#pragma unroll
    for (int j = 0; j < 4; ++j) {
      float x = xs[j];
      float tf = (float)ts[j];
      float e = __expf(-x);
      float p = __builtin_amdgcn_rcpf(1.f + e);
      s_p += p;
      s_t += tf;
      s_pt += p * tf;
      s_bce += x * (1.f - tf) + __logf(1.f + e);
    }
  }
  float r;
  r = block_reduce_256(s_bce, smr, tid);
  if (tid == 0) bceA[blk] = r;
  r = block_reduce_256(s_p, smr, tid);
  if (tid == 0) spA[blk] = r;
  r = block_reduce_256(s_t, smr, tid);
  if (tid == 0) stA[blk] = r;
  r = block_reduce_256(s_pt, smr, tid);
  if (tid == 0) sptA[blk] = r;
}

// ---------------- merged kernel ---------------------------------------------
// Heterogeneous blocks: first NBCE blocks stream BCE/dice partials (memory-
// bound), remaining NSB blocks run the stencil (VALU-bound), 4 independent
// waves each. __launch_bounds__(256, 4): proven shape -- keeps stencil arrays
// register-resident (unified VGPR+AGPR file).
__global__ void __launch_bounds__(256, 4) fused_kernel(
    const float* __restrict__ logits, const int* __restrict__ target,
    float* __restrict__ bceA, float* __restrict__ spA,
    float* __restrict__ stA, float* __restrict__ sptA,
    float* __restrict__ chain_p) {
  if (blockIdx.x < NBCE) {
    bce_body(logits, target, blockIdx.x, bceA, spA, stA, sptA);
    return;
  }
  int tid = threadIdx.x;
  int lane = tid & 63;
  // Force wave-uniform work-item derivation into SGPRs: wv as an expression
  // of tid is thread-varying to the compiler even though it's constant per
  // wave (R6 post-mortem: everything downstream was VGPR, incl. base ptrs).
  int wv = __builtin_amdgcn_readfirstlane(tid >> 6);
  int widx = (blockIdx.x - NBCE) * 4 + wv;  // 0..6655, exact
  int strip = widx % NSTRIP;
  int rest = widx / NSTRIP;
  int band = rest & 15;
  int bz = rest >> 4;  // 0..31
  int img = bz & 15, chain = bz >> 4;
  const float* Lg = logits + (size_t)img * HWc;
  const int* Tg = target + (size_t)img * HWc;
  if (chain == 0)
    fused_body<0>(Lg, Tg, lane, strip, band, bz, chain_p);
  else
    fused_body<1>(Lg, Tg, lane, strip, band, bz, chain_p);
}

// ---------------- finalize ----------------
__global__ void finalize_kernel(const float* __restrict__ bceA,
                                const float* __restrict__ spA,
                                const float* __restrict__ stA,
                                const float* __restrict__ sptA,
                                const float* __restrict__ chain_p,
                                float* __restrict__ out) {
  __shared__ float smr[4];
  __shared__ float smImg[16][3];
  __shared__ double smd[16][2];
  int tid = threadIdx.x;

  float s = 0.f;
  for (int i = tid; i < NBCE; i += 256) s += bceA[i];  // 1024
  float bce_sum = block_reduce_256(s, smr, tid);

  s = 0.f;
  for (int i = tid; i < NWORK; i += 256) s += chain_p[i];  // 6656
  float hd_sum = block_reduce_256(s, smr, tid);

  {
    int img = tid >> 4, part = tid & 15;  // 16 threads per image
    float sp = 0.f, st = 0.f, spt = 0.f;
    for (int j = part; j < 64; j += 16) {  // 64 partials/image, 4 iters
      int idx = img * 64 + j;
      sp += spA[idx];
      st += stA[idx];
      spt += sptA[idx];
    }
#pragma unroll
    for (int off = 8; off > 0; off >>= 1) {
      sp += __shfl_down(sp, off, 16);
      st += __shfl_down(st, off, 16);
      spt += __shfl_down(spt, off, 16);
    }
    if (part == 0) {
      smImg[img][0] = sp;
      smImg[img][1] = st;
      smImg[img][2] = spt;
    }
  }
  __syncthreads();
  if (tid < 16) {
    double sp = smImg[tid][0], st = smImg[tid][1], spt = smImg[tid][2];
    double dice = (2.0 * spt + 1e-6) / (sp + st + 1e-6 + 1e-7);
    double tv = (spt + 1e-6) /
                (spt + 0.7 * (sp - spt) + 0.3 * (st - spt) + 1e-6 + 1e-7);
    smd[tid][0] = 1.0 - dice;
    smd[tid][1] = pow(1.0 - tv, 0.75);
  }
  __syncthreads();
  if (tid == 0) {
    double dice_l = 0.0, ft_l = 0.0;
    for (int i = 0; i < 16; ++i) {
      dice_l += smd[i][0];
      ft_l += smd[i][1];
    }
    dice_l /= 16.0;
    ft_l /= 16.0;
    const double Nd = (double)Nc;
    double bce = (double)bce_sum / Nd;
    double hd = ((double)hd_sum / Nd) / (5.5 + 1e-8);
    out[0] = (float)(bce + dice_l + ft_l + 0.1 * hd);
  }
}

}  // namespace

extern "C" void kernel_launch(void* const* d_in, const int* in_sizes, int n_in,
                              void* d_out, int out_size, void* d_ws,
                              size_t ws_size, hipStream_t stream) {
  const float* logits = (const float*)d_in[0];
  const int* target = (const int*)d_in[1];
  float* out = (float*)d_out;

  // Workspace: only small partial arrays (boundary maps never hit global).
  // All slots below are fully written each launch.
  float* part = (float*)d_ws;
  float* bceA = part;                  // 1024
  float* spA = part + NBCE;            // 1024
  float* stA = part + 2 * NBCE;        // 1024
  float* sptA = part + 3 * NBCE;       // 1024
  float* chain_p = part + 4 * NBCE;    // 6656 = 32*16*13

  fused_kernel<<<dim3(NBCE + NSB), dim3(256), 0, stream>>>(
      logits, target, bceA, spA, stA, sptA, chain_p);
  finalize_kernel<<<1, 256, 0, stream>>>(bceA, spA, stA, sptA, chain_p, out);
}